// Round 13
// baseline (96.265 us; speedup 1.0000x reference)
//
#include <hip/hip_runtime.h>
#include <hip/hip_bf16.h>

// SupConLoss, B=8192, D=128, T=0.1. Output: single fp32 scalar.
//
// Pipeline (3 launches):
//   1) supcon_convert — dtype detection (fp32 vs bf16 feats, i64 vs i32
//      labels); writes features ONCE in MFMA-FRAGMENT ORDER: for col-tile
//      T (16 cols) and k-chunk g, a 64-lane x 16B block at
//      frag[((T*4+g)<<10) + lane*16] = B[n=lane&15][k=g*32+(lane>>4)*8+j].
//      Every A/B fragment load in main is then ONE contiguous 1KB
//      global_load_dwordx4 (8 full 128B lines). Labels -> int32; accbuf
//      zeroed (graph-replay safe ticket).
//   2) supcon_main    — fused bf16-MFMA GEMM (F.F^T) + e/p accumulation.
//      Barrier-free, LDS-free. FOUR named B-register states (bA..bD) in a
//      4x-unrolled rotation -> ~3 col-tiles (plus their labels) in flight
//      -> ~400-600cy latency cover vs the ~200cy L2 latency that the r12
//      1-deep pipeline only just matched (r12 main ~30us vs ~11us issue
//      bound). Per-tile column labels prefetched WITH the fragments
//      (removes a ~200cy bubble before each epilogue). Waves own 32 rows;
//      e/p partials written per-wave (disjoint rows); diag captured to ws.
//   3) supcon_reduce  — e/p partials -> loss. n_i from exact label
//      histogram (n_i = cnt[lab_i]-1). Diagonal removed exactly (same exp2
//      instruction on same input). Last-block-atomic finalization.
//
// Math: with ANY fixed shift M, per row i:
//   mean_log_prob_i = 10*p_i/n_i - M - log(sum_{j!=i} exp(s_ij - M))
// (shift cancels; M=10.5 >= max s_ij for unit-norm). exp folded to exp2:
// exp(10a-10.5) = exp2(a*C1 + C2).
//
// History:
//  r1: launch_bounds(256,4) -> VGPR=64 spill. Never clamp below live set.
//  r2-r4: LDS-staged variants all ~35-46us (2-phase barrier lockstep, m233).
//  r5-r7,r10: four class-sum schemes, all 30-88us latency traps -> p folded
//      back into main's epilogue (r11).
//  r8: sched_barrier graft -> regalloc spill (WRITE 74MB, 144us cold).
//  r9/r10: reg-prefetch clean but strided B-loads (16 half-lines/instr):
//      main 46us flat; NC 8->16 null; OccupancyPercent untrustworthy.
//  r11: infra failure (no data). r12 (=r11): fragment-order pre-swizzle:
//      main ~30us (budget-derived), total 92.4 (session best), absmax 0.
//      Residual vs ~11us issue-bound = prefetch distance 1 == L2 latency.
//      This round: 4-state rotation (3 tiles in flight) + label prefetch.

#define BB 8192
#define DD 128
#define NCLS 100
#define NC 16                 // column chunks (grid.x): 1024 blocks
#define COLCHUNK (BB / NC)    // 512 cols per WG
#define NT (COLCHUNK / 16)    // 32 col-tiles of 16 (divisible by 4)
#define TEMP_INV 10.0f
#define MSHIFT 10.5f
#define C1F 14.426950408889634f    /* 10*log2(e)    */
#define C2F -15.148297929334116f   /* -10.5*log2(e) */

typedef __bf16 bf16x8 __attribute__((ext_vector_type(8)));
typedef float floatx4 __attribute__((ext_vector_type(4)));

__device__ inline float fast_exp2(float x) {
#if __has_builtin(__builtin_amdgcn_exp2f)
    return __builtin_amdgcn_exp2f(x);
#else
    return exp2f(x);
#endif
}

__device__ inline unsigned short f2bf(float f) {           // RTNE fp32->bf16
    unsigned u = __float_as_uint(f);
    return (unsigned short)((u + 0x7FFFu + ((u >> 16) & 1u)) >> 16);
}

// ---- 1) canonicalize into fragment order (+ detect + labels + zero) ----
// Grid 512 x 256: thread handles one 16B output granule G:
//   T = G>>8 (col-tile), g = (G>>6)&3 (k-chunk), l = G&63 (lane slot)
//   col = T*16 + (l&15); kb = g*32 + (l>>4)*8; 8 bf16 from row `col`.
__global__ __launch_bounds__(256) void supcon_convert(
    const void* __restrict__ fin, const void* __restrict__ lin,
    unsigned short* __restrict__ frag, int* __restrict__ lab,
    float* __restrict__ accbuf)
{
    // Per-wave dtype detection (header reads broadcast from L1).
    int lane = threadIdx.x & 63;
    unsigned ue = ((unsigned)((const unsigned short*)fin)[2 * lane]) << 16;
    float fe = __uint_as_float(ue);
    float ve = fe * fe;
    int odd_or = ((const int*)lin)[2 * lane + 1];
#pragma unroll
    for (int m = 1; m < 64; m <<= 1) {
        ve += __shfl_xor(ve, m, 64);
        odd_or |= __shfl_xor(odd_or, m, 64);
    }
    // true bf16 unit rows: sum sq of 64 even slots of row 0 is ~0.5.
    bool f_bf16 = (ve > 0.05f) && (ve < 4.0f);   // NaN-safe: NaN -> false
    bool l_i64  = (odd_or == 0);

    int G = blockIdx.x * 256 + threadIdx.x;      // 131072 granules x 16B
    int T = G >> 8;
    int g = (G >> 6) & 3;
    int l = G & 63;
    int col = T * 16 + (l & 15);
    int kb  = g * 32 + ((l >> 4) << 3);

    ushort4 o0, o1;
    if (!f_bf16) {
        const float4* src = (const float4*)((const float*)fin + (size_t)col * DD + kb);
        float4 a = src[0], b = src[1];
        o0.x = f2bf(a.x); o0.y = f2bf(a.y); o0.z = f2bf(a.z); o0.w = f2bf(a.w);
        o1.x = f2bf(b.x); o1.y = f2bf(b.y); o1.z = f2bf(b.z); o1.w = f2bf(b.w);
    } else {
        const ushort4* src = (const ushort4*)((const unsigned short*)fin + (size_t)col * DD + kb);
        o0 = src[0]; o1 = src[1];
    }
    ushort4* dst = (ushort4*)(frag + (size_t)G * 8);   // coalesced 16B store
    dst[0] = o0; dst[1] = o1;

    const int* L = (const int*)lin;
    if (blockIdx.x < 32) {
        int li = blockIdx.x * 256 + threadIdx.x;
        lab[li] = l_i64 ? L[2 * li] : L[li];
    }
    if (blockIdx.x == 0 && threadIdx.x == 0) {   // zero last-block finals
        accbuf[0] = 0.0f;                        // loss sum
        accbuf[1] = 0.0f;                        // valid count
        ((unsigned*)accbuf)[2] = 0u;             // ticket
    }
}

// Load B fragments + column labels for col-tile `t` (guarded; wave-uniform
// branch). 4 coalesced 1KB loads + one 64B label segment, all prefetched.
#define LOADT(bb, lc, t)                                                      \
    {                                                                         \
        if ((t) < NT) {                                                       \
            const unsigned char* fb =                                         \
                Fbc + ((size_t)((ctile0 + (t)) * 4) << 10) + lane * 16;       \
            _Pragma("unroll")                                                 \
            for (int k = 0; k < 4; ++k)                                       \
                bb[k] = *(const bf16x8*)(fb + (k << 10));                     \
            lc = lab[colchunkbase + (t) * 16 + l16];                          \
        }                                                                     \
    }

// Compute one 16-col tile from register set bb: 8 MFMA + diag + epilogue.
#define COMPT(bb, lc, t)                                                      \
    {                                                                         \
        int colbase = colchunkbase + (t) * 16;                                \
        floatx4 acc[2];                                                       \
        acc[0] = (floatx4){0.f, 0.f, 0.f, 0.f};                               \
        acc[1] = (floatx4){0.f, 0.f, 0.f, 0.f};                               \
        _Pragma("unroll")                                                     \
        for (int k = 0; k < 4; ++k) {                                         \
            acc[0] = __builtin_amdgcn_mfma_f32_16x16x32_bf16(                 \
                afrag[0][k], bb[k], acc[0], 0, 0, 0);                         \
            acc[1] = __builtin_amdgcn_mfma_f32_16x16x32_bf16(                 \
                afrag[1][k], bb[k], acc[1], 0, 0, 0);                         \
        }                                                                     \
        /* Diagonal capture: wave-uniform, rare (2 tiles per wave total). */  \
        {                                                                     \
            unsigned u = (unsigned)(colbase - (rowbase + wid * 32));          \
            if (u < 32u) {                                                    \
                _Pragma("unroll")                                             \
                for (int ti2 = 0; ti2 < 2; ++ti2) {                           \
                    if (u == (unsigned)(ti2 * 16)) {                          \
                        _Pragma("unroll")                                     \
                        for (int r = 0; r < 4; ++r)                           \
                            if (l16 == quad * 4 + r)                          \
                                diag[colbase + l16] = acc[ti2][r];            \
                    }                                                         \
                }                                                             \
            }                                                                 \
        }                                                                     \
        _Pragma("unroll")                                                     \
        for (int ti = 0; ti < 2; ++ti) {                                      \
            _Pragma("unroll")                                                 \
            for (int r = 0; r < 4; ++r) {                                     \
                /* C/D: D[row=quad*4+r][col=l16] (m89/m91 verified) */        \
                int i = ti * 4 + r;                                           \
                float a = acc[ti][r];                                         \
                e_acc[i] += fast_exp2(__builtin_fmaf(a, C1F, C2F));           \
                float peq = ((lc) == lab_row[i]) ? 1.0f : 0.0f;               \
                p_acc[i] = __builtin_fmaf(peq, a, p_acc[i]);                  \
            }                                                                 \
        }                                                                     \
    }

// ---- 2) fused GEMM + e/p partials (4-state reg rotation, no LDS) ----
__global__ __launch_bounds__(256, 2) void supcon_main(
    const unsigned short* __restrict__ Fb, const int* __restrict__ lab,
    float* __restrict__ e_part, float* __restrict__ p_part,
    float* __restrict__ diag)
{
    const int tid  = threadIdx.x;
    const int lane = tid & 63;
    const int wid  = tid >> 6;                   // wave owns 32 rows
    const int quad = lane >> 4;
    const int l16  = lane & 15;

    const int chunk   = blockIdx.x;
    const int rowbase = blockIdx.y * 128;
    const int colchunkbase = chunk * COLCHUNK;
    const int ctile0  = colchunkbase >> 4;

    const unsigned char* Fbc = (const unsigned char*)Fb;

    // A fragments (2 row-tiles x 4 k-chunks) — coalesced 1KB loads.
    bf16x8 afrag[2][4];
#pragma unroll
    for (int ti = 0; ti < 2; ++ti) {
        int rt = (rowbase >> 4) + wid * 2 + ti;
        const unsigned char* fa = Fbc + ((size_t)(rt * 4) << 10) + lane * 16;
#pragma unroll
        for (int k = 0; k < 4; ++k)
            afrag[ti][k] = *(const bf16x8*)(fa + (k << 10));
    }

    int lab_row[8];
#pragma unroll
    for (int ti = 0; ti < 2; ++ti)
#pragma unroll
        for (int r = 0; r < 4; ++r)
            lab_row[ti * 4 + r] = lab[rowbase + wid * 32 + ti * 16 + quad * 4 + r];

    float e_acc[8], p_acc[8];
#pragma unroll
    for (int i = 0; i < 8; ++i) { e_acc[i] = 0.0f; p_acc[i] = 0.0f; }

    // Four named B states (rule #20: static names, never runtime-indexed).
    bf16x8 bA[4], bB[4], bC[4], bD[4];
    int lcA, lcB, lcC, lcD;

    // Prologue: 3 tiles in flight before the first compute.
    LOADT(bA, lcA, 0);
    LOADT(bB, lcB, 1);
    LOADT(bC, lcC, 2);

    for (int t = 0; t < NT; t += 4) {
        LOADT(bD, lcD, t + 3);           // keep 3 tiles ahead throughout
        COMPT(bA, lcA, t);
        LOADT(bA, lcA, t + 4);
        COMPT(bB, lcB, t + 1);
        LOADT(bB, lcB, t + 5);
        COMPT(bC, lcC, t + 2);
        LOADT(bC, lcC, t + 6);
        COMPT(bD, lcD, t + 3);
    }

    // Waves own disjoint rows -> no cross-wave reduce, no LDS, no barrier.
    // Reduce over the 16 column-lanes (xor in l16 bits), then l16==0 lanes
    // (one per quad) write 8 rows each.
#pragma unroll
    for (int i = 0; i < 8; ++i) {
        float e = e_acc[i], p = p_acc[i];
#pragma unroll
        for (int m = 1; m < 16; m <<= 1) {
            e += __shfl_xor(e, m, 64);
            p += __shfl_xor(p, m, 64);
        }
        if (l16 == 0) {
            int row = rowbase + wid * 32 + (i >> 2) * 16 + quad * 4 + (i & 3);
            e_part[(size_t)chunk * BB + row] = e;
            p_part[(size_t)chunk * BB + row] = p;
        }
    }
}

// ---- 3) e/p partials -> scalar loss ----
__global__ __launch_bounds__(256) void supcon_reduce(
    const float* __restrict__ e_part, const float* __restrict__ p_part,
    const int* __restrict__ labels, const float* __restrict__ diag,
    float* __restrict__ accbuf, float* __restrict__ out)
{
    // Exact per-class counts over the whole batch (labels in [0,100)).
    __shared__ int cnt[128];
    if (threadIdx.x < 128) cnt[threadIdx.x] = 0;
    __syncthreads();
    for (int i = threadIdx.x; i < BB; i += 256)
        atomicAdd(&cnt[labels[i]], 1);
    __syncthreads();

    int row = blockIdx.x * 256 + threadIdx.x;    // grid 32
    float e = 0.f, p = 0.f;
#pragma unroll
    for (int c = 0; c < NC; ++c) {
        size_t idx = (size_t)c * BB + row;
        e += e_part[idx]; p += p_part[idx];
    }
    // exact diagonal removal (e: same exp2 instruction on same input as main)
    float d = diag[row];
    e -= fast_exp2(__builtin_fmaf(d, C1F, C2F));
    p -= d;
    int n_i = cnt[labels[row]] - 1;              // integer-exact positive count

    float contrib = 0.f, vld = 0.f;
    if (n_i > 0) {
        vld = 1.0f;
        contrib = -(p * TEMP_INV / (float)n_i - MSHIFT - logf(e));
    }
#pragma unroll
    for (int m = 1; m < 64; m <<= 1) {
        contrib += __shfl_xor(contrib, m, 64);
        vld     += __shfl_xor(vld, m, 64);
    }
    __shared__ float rl[4], rv[4];
    int lane = threadIdx.x & 63, w = threadIdx.x >> 6;
    if (lane == 0) { rl[w] = contrib; rv[w] = vld; }
    __syncthreads();
    if (threadIdx.x == 0) {
        float L = rl[0] + rl[1] + rl[2] + rl[3];
        float V = rv[0] + rv[1] + rv[2] + rv[3];
        atomicAdd(&accbuf[0], L);
        atomicAdd(&accbuf[1], V);
        __threadfence();
        unsigned t = atomicAdd((unsigned*)accbuf + 2, 1u);
        if (t == 31u) {                      // last block: all adds fenced+done
            float Ls = atomicAdd(&accbuf[0], 0.0f);
            float Vs = atomicAdd(&accbuf[1], 0.0f);
            out[0] = (Vs > 0.5f) ? (Ls / Vs) : 0.0f;
        }
    }
}

extern "C" void kernel_launch(void* const* d_in, const int* in_sizes, int n_in,
                              void* d_out, int out_size, void* d_ws, size_t ws_size,
                              hipStream_t stream)
{
    const void* Fin = d_in[0];
    const void* Lin = d_in[1];

    // ws layout (~3.1 MB)
    unsigned short* frag = (unsigned short*)d_ws;                         // 2 MB fragment-order bf16
    int*   lab      = (int*)((char*)d_ws + (size_t)BB * DD * 2);          // 32 KB
    float* e_part   = (float*)((char*)lab + (size_t)BB * 4);              // NC*B floats (512 KB)
    float* p_part   = e_part + (size_t)NC * BB;                           // 512 KB
    float* diag     = p_part + (size_t)NC * BB;                           // B floats
    float* accbuf   = diag + BB;                                          // 3 slots

    supcon_convert<<<BB * DD / 8 / 256, 256, 0, stream>>>(Fin, Lin, frag, lab, accbuf);

    dim3 grid(NC, BB / 128);
    supcon_main<<<grid, 256, 0, stream>>>(frag, lab, e_part, p_part, diag);

    supcon_reduce<<<32, 256, 0, stream>>>(e_part, p_part, lab, diag, accbuf, (float*)d_out);
}

// Round 14
// 93.881 us; speedup vs baseline: 1.0254x; 1.0254x over previous
//
#include <hip/hip_runtime.h>
#include <hip/hip_bf16.h>

// SupConLoss, B=8192, D=128, T=0.1. Output: single fp32 scalar.
//
// Pipeline (3 launches):
//   1) supcon_convert — dtype detection (fp32 vs bf16 feats, i64 vs i32
//      labels); writes features ONCE in MFMA-FRAGMENT ORDER: for col-tile
//      T (16 cols) and k-chunk g, a 64-lane x 16B block at
//      frag[((T*4+g)<<10) + lane*16] = B[n=lane&15][k=g*32+(lane>>4)*8+j].
//      Every A/B fragment load in main is then ONE contiguous 1KB
//      global_load_dwordx4 (8 full 128B lines). Labels -> int32; accbuf
//      zeroed (graph-replay safe ticket).
//   2) supcon_main    — fused bf16-MFMA GEMM (F.F^T) + e/p accumulation.
//      Barrier-free, LDS-free, 2-state reg rotation (r12 structure, the
//      proven optimum at VGPR<=128 16-waves/CU). NEW: 64 ROWS PER WAVE
//      (afrag[4][4]): each B-tile read now feeds 4 MFMAs instead of 2 ->
//      per-CU L1 traffic halves (r12: 16 waves x 32 tiles x 4KB = 2MB/CU
//      ~= 13us of L1 serialization, the best-supported account of main's
//      30us vs the ~8us VALU floor). 512 blocks x 4 waves = 8 waves/CU
//      (VGPR ~175, allowed in (128,256] band; spill only at ~450+).
//      Per-tile labels ride with the fragment load. Waves own disjoint
//      64-row slices; diag captured to ws.
//   3) supcon_reduce  — e/p partials -> loss. n_i from exact label
//      histogram (n_i = cnt[lab_i]-1). Diagonal removed exactly (same exp2
//      instruction on same input). Last-block-atomic finalization.
//
// Math: with ANY fixed shift M, per row i:
//   mean_log_prob_i = 10*p_i/n_i - M - log(sum_{j!=i} exp(s_ij - M))
// (shift cancels; M=10.5 >= max s_ij for unit-norm). exp folded to exp2:
// exp(10a-10.5) = exp2(a*C1 + C2).
//
// History:
//  r1: launch_bounds(256,4) -> VGPR=64 spill. Never clamp below live set.
//  r2-r4: LDS-staged variants all ~35-46us (2-phase barrier lockstep, m233).
//  r5-r7,r10: four class-sum schemes, all 30-88us latency traps -> p folded
//      back into main's epilogue.
//  r8: sched_barrier graft -> regalloc spill (WRITE 74MB, 144us cold).
//  r9/r10: strided B-loads (16 half-lines/instr): main 46us flat.
//  r12: fragment-order pre-swizzle: main ~30us, total 92.4 (best), absmax 0.
//  r13: 4-state prefetch: REGRESSED 96.3 — VGPR crossed the 128 cliff,
//      halved residency. r12 config is the occupancy optimum; main is NOT
//      prefetch-bound. This round: 64 rows/wave halves redundant B reads
//      through L1 (2MB -> 1MB per CU), VALU total unchanged.

#define BB 8192
#define DD 128
#define NCLS 100
#define NC 16                 // column chunks (grid.x): 512 blocks total
#define COLCHUNK (BB / NC)    // 512 cols per WG
#define NT (COLCHUNK / 16)    // 32 col-tiles of 16 (even: 2x-unrolled loop)
#define TEMP_INV 10.0f
#define MSHIFT 10.5f
#define C1F 14.426950408889634f    /* 10*log2(e)    */
#define C2F -15.148297929334116f   /* -10.5*log2(e) */

typedef __bf16 bf16x8 __attribute__((ext_vector_type(8)));
typedef float floatx4 __attribute__((ext_vector_type(4)));

__device__ inline float fast_exp2(float x) {
#if __has_builtin(__builtin_amdgcn_exp2f)
    return __builtin_amdgcn_exp2f(x);
#else
    return exp2f(x);
#endif
}

__device__ inline unsigned short f2bf(float f) {           // RTNE fp32->bf16
    unsigned u = __float_as_uint(f);
    return (unsigned short)((u + 0x7FFFu + ((u >> 16) & 1u)) >> 16);
}

// ---- 1) canonicalize into fragment order (+ detect + labels + zero) ----
// Grid 512 x 256: thread handles one 16B output granule G:
//   T = G>>8 (col-tile), g = (G>>6)&3 (k-chunk), l = G&63 (lane slot)
//   col = T*16 + (l&15); kb = g*32 + (l>>4)*8; 8 bf16 from row `col`.
__global__ __launch_bounds__(256) void supcon_convert(
    const void* __restrict__ fin, const void* __restrict__ lin,
    unsigned short* __restrict__ frag, int* __restrict__ lab,
    float* __restrict__ accbuf)
{
    // Per-wave dtype detection (header reads broadcast from L1).
    int lane = threadIdx.x & 63;
    unsigned ue = ((unsigned)((const unsigned short*)fin)[2 * lane]) << 16;
    float fe = __uint_as_float(ue);
    float ve = fe * fe;
    int odd_or = ((const int*)lin)[2 * lane + 1];
#pragma unroll
    for (int m = 1; m < 64; m <<= 1) {
        ve += __shfl_xor(ve, m, 64);
        odd_or |= __shfl_xor(odd_or, m, 64);
    }
    // true bf16 unit rows: sum sq of 64 even slots of row 0 is ~0.5.
    bool f_bf16 = (ve > 0.05f) && (ve < 4.0f);   // NaN-safe: NaN -> false
    bool l_i64  = (odd_or == 0);

    int G = blockIdx.x * 256 + threadIdx.x;      // 131072 granules x 16B
    int T = G >> 8;
    int g = (G >> 6) & 3;
    int l = G & 63;
    int col = T * 16 + (l & 15);
    int kb  = g * 32 + ((l >> 4) << 3);

    ushort4 o0, o1;
    if (!f_bf16) {
        const float4* src = (const float4*)((const float*)fin + (size_t)col * DD + kb);
        float4 a = src[0], b = src[1];
        o0.x = f2bf(a.x); o0.y = f2bf(a.y); o0.z = f2bf(a.z); o0.w = f2bf(a.w);
        o1.x = f2bf(b.x); o1.y = f2bf(b.y); o1.z = f2bf(b.z); o1.w = f2bf(b.w);
    } else {
        const ushort4* src = (const ushort4*)((const unsigned short*)fin + (size_t)col * DD + kb);
        o0 = src[0]; o1 = src[1];
    }
    ushort4* dst = (ushort4*)(frag + (size_t)G * 8);   // coalesced 16B store
    dst[0] = o0; dst[1] = o1;

    const int* L = (const int*)lin;
    if (blockIdx.x < 32) {
        int li = blockIdx.x * 256 + threadIdx.x;
        lab[li] = l_i64 ? L[2 * li] : L[li];
    }
    if (blockIdx.x == 0 && threadIdx.x == 0) {   // zero last-block finals
        accbuf[0] = 0.0f;                        // loss sum
        accbuf[1] = 0.0f;                        // valid count
        ((unsigned*)accbuf)[2] = 0u;             // ticket
    }
}

// Load B fragments + column labels for col-tile `t`: 4 coalesced 1KB loads
// + one 64B label segment.
#define LOADT(bb, lc, t)                                                      \
    {                                                                         \
        const unsigned char* fb =                                             \
            Fbc + ((size_t)((ctile0 + (t)) * 4) << 10) + lane * 16;           \
        _Pragma("unroll")                                                     \
        for (int k = 0; k < 4; ++k)                                           \
            bb[k] = *(const bf16x8*)(fb + (k << 10));                         \
        lc = lab[colchunkbase + (t) * 16 + l16];                              \
    }

// Compute one 16-col tile x 64 rows from register set bb:
// 16 MFMA + diag + epilogue(16 elements).
#define COMPT(bb, lc, t)                                                      \
    {                                                                         \
        int colbase = colchunkbase + (t) * 16;                                \
        floatx4 acc[4];                                                       \
        _Pragma("unroll")                                                     \
        for (int ti = 0; ti < 4; ++ti) acc[ti] = (floatx4){0.f,0.f,0.f,0.f};  \
        _Pragma("unroll")                                                     \
        for (int k = 0; k < 4; ++k) {                                         \
            _Pragma("unroll")                                                 \
            for (int ti = 0; ti < 4; ++ti)                                    \
                acc[ti] = __builtin_amdgcn_mfma_f32_16x16x32_bf16(            \
                    afrag[ti][k], bb[k], acc[ti], 0, 0, 0);                   \
        }                                                                     \
        /* Diagonal capture: wave-uniform, rare (4 tiles per wave total). */  \
        {                                                                     \
            unsigned u = (unsigned)(colbase - (rowbase + wid * 64));          \
            if (u < 64u) {                                                    \
                _Pragma("unroll")                                             \
                for (int ti2 = 0; ti2 < 4; ++ti2) {                           \
                    if (u == (unsigned)(ti2 * 16)) {                          \
                        _Pragma("unroll")                                     \
                        for (int r = 0; r < 4; ++r)                           \
                            if (l16 == quad * 4 + r)                          \
                                diag[colbase + l16] = acc[ti2][r];            \
                    }                                                         \
                }                                                             \
            }                                                                 \
        }                                                                     \
        _Pragma("unroll")                                                     \
        for (int ti = 0; ti < 4; ++ti) {                                      \
            _Pragma("unroll")                                                 \
            for (int r = 0; r < 4; ++r) {                                     \
                /* C/D: D[row=quad*4+r][col=l16] (m89/m91 verified) */        \
                int i = ti * 4 + r;                                           \
                float a = acc[ti][r];                                         \
                e_acc[i] += fast_exp2(__builtin_fmaf(a, C1F, C2F));           \
                float peq = ((lc) == lab_row[i]) ? 1.0f : 0.0f;               \
                p_acc[i] = __builtin_fmaf(peq, a, p_acc[i]);                  \
            }                                                                 \
        }                                                                     \
    }

// ---- 2) fused GEMM + e/p partials (64 rows/wave, 2-state rotation) ----
__global__ __launch_bounds__(256, 2) void supcon_main(
    const unsigned short* __restrict__ Fb, const int* __restrict__ lab,
    float* __restrict__ e_part, float* __restrict__ p_part,
    float* __restrict__ diag)
{
    const int tid  = threadIdx.x;
    const int lane = tid & 63;
    const int wid  = tid >> 6;                   // wave owns 64 rows
    const int quad = lane >> 4;
    const int l16  = lane & 15;

    const int chunk   = blockIdx.x;
    const int rowbase = blockIdx.y * 256;        // block owns 256 rows
    const int colchunkbase = chunk * COLCHUNK;
    const int ctile0  = colchunkbase >> 4;

    const unsigned char* Fbc = (const unsigned char*)Fb;

    // A fragments (4 row-tiles x 4 k-chunks) — coalesced 1KB loads.
    bf16x8 afrag[4][4];
#pragma unroll
    for (int ti = 0; ti < 4; ++ti) {
        int rt = (rowbase >> 4) + wid * 4 + ti;
        const unsigned char* fa = Fbc + ((size_t)(rt * 4) << 10) + lane * 16;
#pragma unroll
        for (int k = 0; k < 4; ++k)
            afrag[ti][k] = *(const bf16x8*)(fa + (k << 10));
    }

    int lab_row[16];
#pragma unroll
    for (int ti = 0; ti < 4; ++ti)
#pragma unroll
        for (int r = 0; r < 4; ++r)
            lab_row[ti * 4 + r] = lab[rowbase + wid * 64 + ti * 16 + quad * 4 + r];

    float e_acc[16], p_acc[16];
#pragma unroll
    for (int i = 0; i < 16; ++i) { e_acc[i] = 0.0f; p_acc[i] = 0.0f; }

    // Two named B states (rule #20: static names, never runtime-indexed).
    bf16x8 b0[4], b1[4];
    int lc0, lc1;
    LOADT(b0, lc0, 0);

    for (int t = 0; t < NT; t += 2) {
        LOADT(b1, lc1, t + 1);           // issue-early
        COMPT(b0, lc0, t);               // use-late
        if (t + 2 < NT) LOADT(b0, lc0, t + 2);
        COMPT(b1, lc1, t + 1);
    }

    // Waves own disjoint rows -> no cross-wave reduce, no LDS, no barrier.
    // Reduce over the 16 column-lanes (xor in l16 bits), then l16==0 lanes
    // (one per quad) write 16 rows each.
#pragma unroll
    for (int i = 0; i < 16; ++i) {
        float e = e_acc[i], p = p_acc[i];
#pragma unroll
        for (int m = 1; m < 16; m <<= 1) {
            e += __shfl_xor(e, m, 64);
            p += __shfl_xor(p, m, 64);
        }
        if (l16 == 0) {
            int row = rowbase + wid * 64 + (i >> 2) * 16 + quad * 4 + (i & 3);
            e_part[(size_t)chunk * BB + row] = e;
            p_part[(size_t)chunk * BB + row] = p;
        }
    }
}

// ---- 3) e/p partials -> scalar loss ----
__global__ __launch_bounds__(256) void supcon_reduce(
    const float* __restrict__ e_part, const float* __restrict__ p_part,
    const int* __restrict__ labels, const float* __restrict__ diag,
    float* __restrict__ accbuf, float* __restrict__ out)
{
    // Exact per-class counts over the whole batch (labels in [0,100)).
    __shared__ int cnt[128];
    if (threadIdx.x < 128) cnt[threadIdx.x] = 0;
    __syncthreads();
    for (int i = threadIdx.x; i < BB; i += 256)
        atomicAdd(&cnt[labels[i]], 1);
    __syncthreads();

    int row = blockIdx.x * 256 + threadIdx.x;    // grid 32
    float e = 0.f, p = 0.f;
#pragma unroll
    for (int c = 0; c < NC; ++c) {
        size_t idx = (size_t)c * BB + row;
        e += e_part[idx]; p += p_part[idx];
    }
    // exact diagonal removal (e: same exp2 instruction on same input as main)
    float d = diag[row];
    e -= fast_exp2(__builtin_fmaf(d, C1F, C2F));
    p -= d;
    int n_i = cnt[labels[row]] - 1;              // integer-exact positive count

    float contrib = 0.f, vld = 0.f;
    if (n_i > 0) {
        vld = 1.0f;
        contrib = -(p * TEMP_INV / (float)n_i - MSHIFT - logf(e));
    }
#pragma unroll
    for (int m = 1; m < 64; m <<= 1) {
        contrib += __shfl_xor(contrib, m, 64);
        vld     += __shfl_xor(vld, m, 64);
    }
    __shared__ float rl[4], rv[4];
    int lane = threadIdx.x & 63, w = threadIdx.x >> 6;
    if (lane == 0) { rl[w] = contrib; rv[w] = vld; }
    __syncthreads();
    if (threadIdx.x == 0) {
        float L = rl[0] + rl[1] + rl[2] + rl[3];
        float V = rv[0] + rv[1] + rv[2] + rv[3];
        atomicAdd(&accbuf[0], L);
        atomicAdd(&accbuf[1], V);
        __threadfence();
        unsigned t = atomicAdd((unsigned*)accbuf + 2, 1u);
        if (t == 31u) {                      // last block: all adds fenced+done
            float Ls = atomicAdd(&accbuf[0], 0.0f);
            float Vs = atomicAdd(&accbuf[1], 0.0f);
            out[0] = (Vs > 0.5f) ? (Ls / Vs) : 0.0f;
        }
    }
}

extern "C" void kernel_launch(void* const* d_in, const int* in_sizes, int n_in,
                              void* d_out, int out_size, void* d_ws, size_t ws_size,
                              hipStream_t stream)
{
    const void* Fin = d_in[0];
    const void* Lin = d_in[1];

    // ws layout (~3.1 MB)
    unsigned short* frag = (unsigned short*)d_ws;                         // 2 MB fragment-order bf16
    int*   lab      = (int*)((char*)d_ws + (size_t)BB * DD * 2);          // 32 KB
    float* e_part   = (float*)((char*)lab + (size_t)BB * 4);              // NC*B floats (512 KB)
    float* p_part   = e_part + (size_t)NC * BB;                           // 512 KB
    float* diag     = p_part + (size_t)NC * BB;                           // B floats
    float* accbuf   = diag + BB;                                          // 3 slots

    supcon_convert<<<BB * DD / 8 / 256, 256, 0, stream>>>(Fin, Lin, frag, lab, accbuf);

    dim3 grid(NC, BB / 256);
    supcon_main<<<grid, 256, 0, stream>>>(frag, lab, e_part, p_part, diag);

    supcon_reduce<<<32, 256, 0, stream>>>(e_part, p_part, lab, diag, accbuf, (float*)d_out);
}